// Round 4
// baseline (9006.918 us; speedup 1.0000x reference)
//
#include <hip/hip_runtime.h>
#include <hip/hip_bf16.h>

// LSTM: T=512, B=64, D_IN=512, D_LAT=1024.
// Phase 1: xg = x @ Wx^T + b (bf16 MFMA, pre-permuted bf16 output).
// Phase 2: persistent, 32 WGs x 256 thr (4 N-split waves, each wave: 64 batch
//   rows x 32 gate cols, 256 MFMA/step). Wh in VGPRs (256/lane). h exchanged
//   via relaxed agent-scope 8B atomics in a bank-swizzled global layout,
//   staged cooperatively into ONE 64KB LDS buffer in TWO passes
//   (rows 0..31 -> MFMA m=0,1 ; rows 32..63 -> MFMA m=2,3), second pass's
//   loads issued before the first MFMA block to hide IF$ latency.

typedef __attribute__((ext_vector_type(8))) short short8;
typedef __attribute__((ext_vector_type(4))) short short4v;
typedef __attribute__((ext_vector_type(4))) float f32x4;
typedef unsigned long long ull;

#define T_STEPS 512
#define BATCH   64
#define DIN     512
#define DLAT    1024
#define NWG2    32

#define WS_H    4096                     // 2 x 128KB h buffers
#define WS_XG   (4096 + 262144)          // 256 MiB xg

#define MFMA(a, b, c) __builtin_amdgcn_mfma_f32_16x16x32_bf16((a), (b), (c), 0, 0, 0)
#define AT_LD(p)    __hip_atomic_load((p), __ATOMIC_RELAXED, __HIP_MEMORY_SCOPE_AGENT)
#define AT_ST(p, v) __hip_atomic_store((p), (v), __ATOMIC_RELAXED, __HIP_MEMORY_SCOPE_AGENT)

static __device__ __forceinline__ unsigned short f2bf(float f) {
  unsigned u = __builtin_bit_cast(unsigned, f);
  u = (u + 0x7FFFu + ((u >> 16) & 1u)) >> 16;   // RNE
  return (unsigned short)u;
}
static __device__ __forceinline__ float bf2f(unsigned short s) {
  unsigned u = ((unsigned)s) << 16;
  return __builtin_bit_cast(float, u);
}
static __device__ __forceinline__ float sigf(float x) {
  return 1.0f / (1.0f + __expf(-x));
}
static __device__ __forceinline__ float tanhfast(float x) {
  return 2.0f / (1.0f + __expf(-2.0f * x)) - 1.0f;
}
static __device__ __forceinline__ short8 packbf(f32x4 a, f32x4 b) {
  short8 s;
  s[0]=(short)f2bf(a[0]); s[1]=(short)f2bf(a[1]); s[2]=(short)f2bf(a[2]); s[3]=(short)f2bf(a[3]);
  s[4]=(short)f2bf(b[0]); s[5]=(short)f2bf(b[1]); s[6]=(short)f2bf(b[2]); s[7]=(short)f2bf(b[3]);
  return s;
}

// ---------------- Phase 1: xg = x @ Wx^T + bias -----------------------------
__global__ __launch_bounds__(256, 2) void lstm_phase1(
    const float* __restrict__ x,
    const float* __restrict__ Wf, const float* __restrict__ bfp,
    const float* __restrict__ Wi, const float* __restrict__ bip,
    const float* __restrict__ Wc, const float* __restrict__ bcp,
    const float* __restrict__ Wo, const float* __restrict__ bop,
    unsigned short* __restrict__ xg)
{
  __shared__ __align__(16) short lds[BATCH * DIN];
  const int tid  = threadIdx.x;
  const int nb   = blockIdx.x;    // 0..31
  const int tb4  = blockIdx.y;    // 0..127
  const int lane = tid & 63;
  const int wv   = tid >> 6;
  const int cc   = lane & 15;
  const int q    = lane >> 4;

  const int wg = nb * 4 + wv;     // N-slice 0..127
  const int jj = wg * 8 + (cc & 7);
  short8 bw[2][16];
  #pragma unroll
  for (int T = 0; T < 2; ++T) {
    const float* Wp = (T == 0) ? (cc < 8 ? Wf : Wi) : (cc < 8 ? Wc : Wo);
    const float* base = Wp + (size_t)jj * (DIN + DLAT);
    #pragma unroll
    for (int k = 0; k < 16; ++k) {
      const f32x4* p = (const f32x4*)(base + k * 32 + q * 8);
      bw[T][k] = packbf(p[0], p[1]);
    }
  }
  float biasv[2];
  biasv[0] = (cc < 8 ? bfp : bip)[jj];
  biasv[1] = (cc < 8 ? bcp : bop)[jj];

  for (int tt = 0; tt < 4; ++tt) {
    const int tb = tb4 * 4 + tt;
    const float* xs = x + (size_t)tb * (BATCH * DIN);
    #pragma unroll
    for (int it = 0; it < 16; ++it) {
      int c = tid + 256 * it;
      int row = c >> 6, kc = c & 63;
      const f32x4* p = (const f32x4*)(xs + row * DIN + kc * 8);
      f32x4 v0 = p[0], v1 = p[1];
      int byte = (row * (DIN * 2) + kc * 16) ^ ((row & 7) << 4);
      *(short8*)((char*)lds + byte) = packbf(v0, v1);
    }
    __syncthreads();

    f32x4 acc[4][2] = {};
    #pragma unroll
    for (int k = 0; k < 16; ++k) {
      #pragma unroll
      for (int m = 0; m < 4; ++m) {
        int row = m * 16 + cc;
        int byte = (row * (DIN * 2) + (k * 32 + q * 8) * 2) ^ ((row & 7) << 4);
        short8 a = *(const short8*)((const char*)lds + byte);
        acc[m][0] = MFMA(a, bw[0][k], acc[m][0]);
        acc[m][1] = MFMA(a, bw[1][k], acc[m][1]);
      }
    }
    __syncthreads();

    #pragma unroll
    for (int T = 0; T < 2; ++T) {
      float bias = biasv[T];
      #pragma unroll
      for (int m = 0; m < 4; ++m) {
        f32x4 g = acc[m][T];
        short4v s;
        s[0] = (short)f2bf(g[0] + bias);
        s[1] = (short)f2bf(g[1] + bias);
        s[2] = (short)f2bf(g[2] + bias);
        s[3] = (short)f2bf(g[3] + bias);
        size_t idx = (size_t)tb * 1024 + (size_t)wg * 8 + m * 2 + T;
        *(short4v*)(xg + idx * 256 + lane * 4) = s;
      }
    }
  }
}

// ---------------- Phase 2: persistent recurrence ----------------------------
__global__ __launch_bounds__(256, 1) void lstm_phase2(
    const float* __restrict__ Wf, const float* __restrict__ Wi,
    const float* __restrict__ Wc, const float* __restrict__ Wo,
    const unsigned short* __restrict__ xg,
    unsigned short* __restrict__ hbuf,      // 2 x swizzled [64][1024] bf16
    unsigned int* __restrict__ flags,       // NWG2 monotonic arrival flags
    float* __restrict__ out)
{
  __shared__ __align__(16) ull stage[8192];               // 64 KB, reused 2x/step
  unsigned short* lds_h = (unsigned short*)stage;         // overlay [64][32]
  float*          lds_o = (float*)((char*)stage + 4096);  // overlay [64][32]

  const int tid  = threadIdx.x;
  const int lane = tid & 63;
  const int wv   = tid >> 6;        // N-group 0..3
  const int wg   = blockIdx.x;      // 0..31
  const int cc   = lane & 15;
  const int q    = lane >> 4;
  const int swz  = (cc & 7) << 4;
  const int jj   = wg * 32 + wv * 8 + (cc & 7);

  // Wh fragments -> registers (256 VGPR/lane)
  short8 wh[2][32];
  #pragma unroll
  for (int T = 0; T < 2; ++T) {
    const float* Wp = (T == 0) ? (cc < 8 ? Wf : Wi) : (cc < 8 ? Wc : Wo);
    const float* base = Wp + (size_t)jj * (DIN + DLAT) + DIN;
    #pragma unroll
    for (int k = 0; k < 32; ++k) {
      const f32x4* p = (const f32x4*)(base + k * 32 + q * 8);
      wh[T][k] = packbf(p[0], p[1]);
    }
  }

  f32x4 cst[4] = {};
  const unsigned short* xbase = xg + (size_t)(wg * 32 + wv * 8) * 256 + lane * 4;
  short4v xp0[4], xp1[4];
  #pragma unroll
  for (int m = 0; m < 4; ++m) {
    xp0[m] = *(const short4v*)(xbase + (m * 2 + 0) * 256);
    xp1[m] = *(const short4v*)(xbase + (m * 2 + 1) * 256);
  }

  const ull* hb = (const ull*)hbuf;

  for (int t = 0; t < T_STEPS; ++t) {
    f32x4 acc[4][2] = {};

    if (t > 0) {
      // ---- wait for h_{t-1} (every wave polls all 32 flags)
      {
        const unsigned int* fp = flags + (lane & 31);
        for (;;) {
          unsigned a = AT_LD(fp);
          if (__all(a >= (unsigned)t)) break;
          __builtin_amdgcn_s_sleep(1);
        }
      }
      const ull* hsrc = hb + (size_t)((t & 1) ^ 1) * 16384;
      const char* sb = (const char*)stage;
      ull areg[32];

      // ---- half 0 (batch rows 0..31): coalesced load -> LDS
      #pragma unroll
      for (int i = 0; i < 32; ++i) areg[i] = AT_LD(hsrc + i * 256 + tid);
      #pragma unroll
      for (int i = 0; i < 32; ++i) stage[i * 256 + tid] = areg[i];
      __syncthreads();                                     // half0 staged

      // ---- issue half-1 loads, then MFMA over rows 0..31 (latency overlap)
      #pragma unroll
      for (int i = 0; i < 32; ++i) areg[i] = AT_LD(hsrc + 8192 + i * 256 + tid);
      #pragma unroll
      for (int m = 0; m < 2; ++m) {
        const int rb = (m * 16 + cc) * 2048;
        #pragma unroll
        for (int k = 0; k < 32; ++k) {
          short8 a = *(const short8*)(sb + ((rb + k * 64 + q * 16) ^ swz));
          acc[m][0] = MFMA(a, wh[0][k], acc[m][0]);
          acc[m][1] = MFMA(a, wh[1][k], acc[m][1]);
        }
      }
      __syncthreads();                                     // half0 reads done

      // ---- half 1 (batch rows 32..63) into the SAME buffer
      #pragma unroll
      for (int i = 0; i < 32; ++i) stage[i * 256 + tid] = areg[i];
      __syncthreads();                                     // half1 staged
      #pragma unroll
      for (int m = 2; m < 4; ++m) {
        const int rb = ((m - 2) * 16 + cc) * 2048;         // local rows 0..31
        #pragma unroll
        for (int k = 0; k < 32; ++k) {
          short8 a = *(const short8*)(sb + ((rb + k * 64 + q * 16) ^ swz));
          acc[m][0] = MFMA(a, wh[0][k], acc[m][0]);
          acc[m][1] = MFMA(a, wh[1][k], acc[m][1]);
        }
      }
      __syncthreads();                      // stage dead -> overlays safe
    }

    // ---- gates for all 4 M-tiles
    const bool lo = (cc < 8);
    #pragma unroll
    for (int m = 0; m < 4; ++m) {
      f32x4 g0, g1;
      #pragma unroll
      for (int r = 0; r < 4; ++r) {
        g0[r] = acc[m][0][r] + bf2f((unsigned short)xp0[m][r]);
        g1[r] = acc[m][1][r] + bf2f((unsigned short)xp1[m][r]);
      }
      f32x4 g0x, g1x;
      #pragma unroll
      for (int r = 0; r < 4; ++r) {
        g0x[r] = __shfl_xor(g0[r], 8, 64);
        g1x[r] = __shfl_xor(g1[r], 8, 64);
      }
      float hv[4];
      #pragma unroll
      for (int r = 0; r < 4; ++r) {
        float fpre = lo ? g0[r]  : g0x[r];
        float ipre = lo ? g0x[r] : g0[r];
        float cpre = lo ? g1[r]  : g1x[r];
        float opre = lo ? g1x[r] : g1[r];
        float fg = sigf(fpre), ig = sigf(ipre), cd = tanhfast(cpre), og = sigf(opre);
        float cn = fg * cst[m][r] + ig * cd;
        cst[m][r] = cn;
        hv[r] = og * tanhfast(cn);
      }
      if (lo) {
        #pragma unroll
        for (int r = 0; r < 4; ++r) {
          int b = m * 16 + q * 4 + r;
          lds_h[b * 32 + wv * 8 + cc] = f2bf(hv[r]);
          lds_o[b * 32 + wv * 8 + cc] = hv[r];
        }
      }
    }
    __syncthreads();   // transpose complete

    // ---- h store (swizzled global layout), 2x 8B agent atomics per thread
    {
      const int row = tid >> 2, i = tid & 3;
      ull v0 = ((const ull*)lds_h)[row * 8 + i * 2 + 0];
      ull v1 = ((const ull*)lds_h)[row * 8 + i * 2 + 1];
      char* hw = (char*)hbuf + (size_t)(t & 1) * 131072;
      int base = row * 2048 + wg * 64 + i * 16;
      AT_ST((ull*)(hw + ((base + 0) ^ ((row & 7) << 4))), v0);
      AT_ST((ull*)(hw + ((base + 8) ^ ((row & 7) << 4))), v1);
    }
    asm volatile("s_waitcnt vmcnt(0)" ::: "memory");   // h stores visible
    __syncthreads();                                   // all waves drained
    if (tid == 0) AT_ST(flags + wg, (unsigned)(t + 1));

    // ---- out store + xg prefetch, off the critical path
    {
      const int row = tid >> 2, i = tid & 3;
      const f32x4* src = (const f32x4*)(lds_o + row * 32 + i * 8);
      f32x4 o0 = src[0], o1 = src[1];
      float* op = out + (size_t)t * (BATCH * DLAT) + row * DLAT + wg * 32 + i * 8;
      *(f32x4*)op = o0;
      *(f32x4*)(op + 4) = o1;
    }
    {
      int tn = (t + 1 < T_STEPS) ? t + 1 : t;
      const unsigned short* xn = xbase + ((size_t)tn << 18);
      #pragma unroll
      for (int m = 0; m < 4; ++m) {
        xp0[m] = *(const short4v*)(xn + (m * 2 + 0) * 256);
        xp1[m] = *(const short4v*)(xn + (m * 2 + 1) * 256);
      }
    }
    __syncthreads();   // protect overlays from next step's staging writes
  }
}

extern "C" void kernel_launch(void* const* d_in, const int* in_sizes, int n_in,
                              void* d_out, int out_size, void* d_ws, size_t ws_size,
                              hipStream_t stream) {
  (void)in_sizes; (void)n_in; (void)out_size; (void)ws_size;
  const float* x   = (const float*)d_in[0];
  const float* Wf  = (const float*)d_in[1];
  const float* bfp = (const float*)d_in[2];
  const float* Wi  = (const float*)d_in[3];
  const float* bip = (const float*)d_in[4];
  const float* Wc  = (const float*)d_in[5];
  const float* bcp = (const float*)d_in[6];
  const float* Wo  = (const float*)d_in[7];
  const float* bop = (const float*)d_in[8];
  float* out = (float*)d_out;

  unsigned int*   flags = (unsigned int*)d_ws;
  unsigned short* hbuf  = (unsigned short*)((char*)d_ws + WS_H);
  unsigned short* xg    = (unsigned short*)((char*)d_ws + WS_XG);

  hipMemsetAsync(d_ws, 0, 4096, stream);   // reset arrival flags each call
  lstm_phase1<<<dim3(32, 128), 256, 0, stream>>>(x, Wf, bfp, Wi, bip, Wc, bcp, Wo, bop, xg);
  lstm_phase2<<<dim3(NWG2), 256, 0, stream>>>(Wf, Wi, Wc, Wo, xg, hbuf, flags, out);
}

// Round 5
// 8420.736 us; speedup vs baseline: 1.0696x; 1.0696x over previous
//
#include <hip/hip_runtime.h>
#include <hip/hip_bf16.h>

// LSTM: T=512, B=64, D_IN=512, D_LAT=1024.
// Phase 1: xg = x @ Wx^T + b (bf16 MFMA, pre-permuted bf16 output).
// Phase 2: persistent, 128 WGs x 256 thr (wave = 16 batch rows x 32 gate cols,
//   64 MFMA/step). Wh in VGPRs. h exchange rebuilt:
//   - h_t lives in out[t] (fresh address per step -> L2-cacheable: kernel-start
//     invalidate + first-touch means normal cached loads are coherent)
//   - producers: sc1 (agent) 8B stores of out rows -> MALL, vmcnt drain, flag
//   - consumers: poll flags (sc1), then PLAIN cached f32 loads of out[t-1];
//     each XCD L2 pulls 256KB once and multicasts to its 16 WGs
//   - f32 -> bf16 fragment conversion in-register via v_cvt_pk_bf16_f32

typedef __attribute__((ext_vector_type(8))) short short8;
typedef __attribute__((ext_vector_type(4))) short short4v;
typedef __attribute__((ext_vector_type(4))) float f32x4;
typedef unsigned long long ull;

#define T_STEPS 512
#define BATCH   64
#define DIN     512
#define DLAT    1024
#define NWG     128

#define WS_XG   4096                     // xg right after flags

#define MFMA(a, b, c) __builtin_amdgcn_mfma_f32_16x16x32_bf16((a), (b), (c), 0, 0, 0)
#define AT_LD(p)    __hip_atomic_load((p), __ATOMIC_RELAXED, __HIP_MEMORY_SCOPE_AGENT)
#define AT_ST(p, v) __hip_atomic_store((p), (v), __ATOMIC_RELAXED, __HIP_MEMORY_SCOPE_AGENT)

static __device__ __forceinline__ unsigned short f2bf(float f) {
  unsigned u = __builtin_bit_cast(unsigned, f);
  u = (u + 0x7FFFu + ((u >> 16) & 1u)) >> 16;   // RNE
  return (unsigned short)u;
}
static __device__ __forceinline__ float bf2f(unsigned short s) {
  unsigned u = ((unsigned)s) << 16;
  return __builtin_bit_cast(float, u);
}
static __device__ __forceinline__ float sigf(float x) {
  return 1.0f / (1.0f + __expf(-x));
}
static __device__ __forceinline__ float tanhfast(float x) {
  return 2.0f / (1.0f + __expf(-2.0f * x)) - 1.0f;
}
static __device__ __forceinline__ short8 packbf(f32x4 a, f32x4 b) {
  short8 s;
  s[0]=(short)f2bf(a[0]); s[1]=(short)f2bf(a[1]); s[2]=(short)f2bf(a[2]); s[3]=(short)f2bf(a[3]);
  s[4]=(short)f2bf(b[0]); s[5]=(short)f2bf(b[1]); s[6]=(short)f2bf(b[2]); s[7]=(short)f2bf(b[3]);
  return s;
}
// HW RNE f32->bf16 pack (2 per instr); elem order matches packbf
static __device__ __forceinline__ short8 cvt8(f32x4 a, f32x4 b) {
  union { unsigned u[4]; short8 s; } r;
  asm("v_cvt_pk_bf16_f32 %0, %1, %2" : "=v"(r.u[0]) : "v"(a[0]), "v"(a[1]));
  asm("v_cvt_pk_bf16_f32 %0, %1, %2" : "=v"(r.u[1]) : "v"(a[2]), "v"(a[3]));
  asm("v_cvt_pk_bf16_f32 %0, %1, %2" : "=v"(r.u[2]) : "v"(b[0]), "v"(b[1]));
  asm("v_cvt_pk_bf16_f32 %0, %1, %2" : "=v"(r.u[3]) : "v"(b[2]), "v"(b[3]));
  return r.s;
}

// ---------------- Phase 1: xg = x @ Wx^T + bias -----------------------------
__global__ __launch_bounds__(256, 2) void lstm_phase1(
    const float* __restrict__ x,
    const float* __restrict__ Wf, const float* __restrict__ bfp,
    const float* __restrict__ Wi, const float* __restrict__ bip,
    const float* __restrict__ Wc, const float* __restrict__ bcp,
    const float* __restrict__ Wo, const float* __restrict__ bop,
    unsigned short* __restrict__ xg)
{
  __shared__ __align__(16) short lds[BATCH * DIN];
  const int tid  = threadIdx.x;
  const int nb   = blockIdx.x;    // 0..31
  const int tb4  = blockIdx.y;    // 0..127
  const int lane = tid & 63;
  const int wv   = tid >> 6;
  const int cc   = lane & 15;
  const int q    = lane >> 4;

  const int wg = nb * 4 + wv;     // N-slice 0..127
  const int jj = wg * 8 + (cc & 7);
  short8 bw[2][16];
  #pragma unroll
  for (int T = 0; T < 2; ++T) {
    const float* Wp = (T == 0) ? (cc < 8 ? Wf : Wi) : (cc < 8 ? Wc : Wo);
    const float* base = Wp + (size_t)jj * (DIN + DLAT);
    #pragma unroll
    for (int k = 0; k < 16; ++k) {
      const f32x4* p = (const f32x4*)(base + k * 32 + q * 8);
      bw[T][k] = packbf(p[0], p[1]);
    }
  }
  float biasv[2];
  biasv[0] = (cc < 8 ? bfp : bip)[jj];
  biasv[1] = (cc < 8 ? bcp : bop)[jj];

  for (int tt = 0; tt < 4; ++tt) {
    const int tb = tb4 * 4 + tt;
    const float* xs = x + (size_t)tb * (BATCH * DIN);
    #pragma unroll
    for (int it = 0; it < 16; ++it) {
      int c = tid + 256 * it;
      int row = c >> 6, kc = c & 63;
      const f32x4* p = (const f32x4*)(xs + row * DIN + kc * 8);
      f32x4 v0 = p[0], v1 = p[1];
      int byte = (row * (DIN * 2) + kc * 16) ^ ((row & 7) << 4);
      *(short8*)((char*)lds + byte) = packbf(v0, v1);
    }
    __syncthreads();

    f32x4 acc[4][2] = {};
    #pragma unroll
    for (int k = 0; k < 16; ++k) {
      #pragma unroll
      for (int m = 0; m < 4; ++m) {
        int row = m * 16 + cc;
        int byte = (row * (DIN * 2) + (k * 32 + q * 8) * 2) ^ ((row & 7) << 4);
        short8 a = *(const short8*)((const char*)lds + byte);
        acc[m][0] = MFMA(a, bw[0][k], acc[m][0]);
        acc[m][1] = MFMA(a, bw[1][k], acc[m][1]);
      }
    }
    __syncthreads();

    #pragma unroll
    for (int T = 0; T < 2; ++T) {
      float bias = biasv[T];
      #pragma unroll
      for (int m = 0; m < 4; ++m) {
        f32x4 g = acc[m][T];
        short4v s;
        s[0] = (short)f2bf(g[0] + bias);
        s[1] = (short)f2bf(g[1] + bias);
        s[2] = (short)f2bf(g[2] + bias);
        s[3] = (short)f2bf(g[3] + bias);
        size_t idx = ((((size_t)tb * NWG + wg) * 4 + m) * 2 + T) * 64 + lane;
        *(short4v*)(xg + idx * 4) = s;
      }
    }
  }
}

// ---------------- Phase 2: persistent recurrence ----------------------------
__global__ __launch_bounds__(256, 1) void lstm_phase2(
    const float* __restrict__ Wf, const float* __restrict__ Wi,
    const float* __restrict__ Wc, const float* __restrict__ Wo,
    const unsigned short* __restrict__ xg,
    unsigned int* __restrict__ flags,       // NWG monotonic arrival flags
    float* __restrict__ out)                // out[t] IS h_t (f32)
{
  __shared__ float lds_o[4][16][8];         // per-WG 64 rows x 8 cols transpose

  const int tid  = threadIdx.x;
  const int lane = tid & 63;
  const int wv   = tid >> 6;        // M-tile (batch group) 0..3
  const int wg   = blockIdx.x;      // 0..127
  const int cc   = lane & 15;
  const int q    = lane >> 4;
  const int jj   = wg * 8 + (cc & 7);

  // Wh fragments -> registers
  short8 wh[2][32];
  #pragma unroll
  for (int T = 0; T < 2; ++T) {
    const float* Wp = (T == 0) ? (cc < 8 ? Wf : Wi) : (cc < 8 ? Wc : Wo);
    const float* base = Wp + (size_t)jj * (DIN + DLAT) + DIN;
    #pragma unroll
    for (int k = 0; k < 32; ++k) {
      const f32x4* p = (const f32x4*)(base + k * 32 + q * 8);
      wh[T][k] = packbf(p[0], p[1]);
    }
  }

  f32x4 cst = {0.f, 0.f, 0.f, 0.f};
  const unsigned short* xbase = xg + (((size_t)wg * 4 + wv) * 2) * 256 + (size_t)lane * 4;
  const int arow = wv * 16 + cc;

  short4v xp0 = *(const short4v*)(xbase);
  short4v xp1 = *(const short4v*)(xbase + 256);

  for (int t = 0; t < T_STEPS; ++t) {
    f32x4 acc0 = {0.f,0.f,0.f,0.f}, acc1 = {0.f,0.f,0.f,0.f};

    if (t > 0) {
      // ---- wait for h_{t-1}: every wave polls all 128 flags independently
      {
        const unsigned int* fp = flags + lane;
        for (;;) {
          unsigned a1 = AT_LD(fp);
          unsigned a2 = AT_LD(fp + 64);
          if (__all(a1 >= (unsigned)t && a2 >= (unsigned)t)) break;
          __builtin_amdgcn_s_sleep(1);
        }
      }
      // ---- h_{t-1} = out[t-1], PLAIN cached f32 loads (L2-multicast)
      const float* hrow = out + (((size_t)(t - 1)) << 16) + arow * DLAT + q * 8;
      #pragma unroll
      for (int chunk = 0; chunk < 2; ++chunk) {
        f32x4 r0[16], r1[16];
        #pragma unroll
        for (int k = 0; k < 16; ++k) {
          const f32x4* p = (const f32x4*)(hrow + (chunk * 16 + k) * 32);
          r0[k] = p[0];
          r1[k] = p[1];
        }
        #pragma unroll
        for (int k = 0; k < 16; ++k) {
          short8 a = cvt8(r0[k], r1[k]);
          acc0 = MFMA(a, wh[0][chunk * 16 + k], acc0);
          acc1 = MFMA(a, wh[1][chunk * 16 + k], acc1);
        }
      }
    }

    // ---- gates
    f32x4 g0, g1;
    #pragma unroll
    for (int r = 0; r < 4; ++r) {
      g0[r] = acc0[r] + bf2f((unsigned short)xp0[r]);
      g1[r] = acc1[r] + bf2f((unsigned short)xp1[r]);
    }
    f32x4 g0x, g1x;
    #pragma unroll
    for (int r = 0; r < 4; ++r) {
      g0x[r] = __shfl_xor(g0[r], 8, 64);
      g1x[r] = __shfl_xor(g1[r], 8, 64);
    }
    const bool lo = (cc < 8);
    float hv[4];
    #pragma unroll
    for (int r = 0; r < 4; ++r) {
      float fpre = lo ? g0[r]  : g0x[r];
      float ipre = lo ? g0x[r] : g0[r];
      float cpre = lo ? g1[r]  : g1x[r];
      float opre = lo ? g1x[r] : g1[r];
      float fg = sigf(fpre), ig = sigf(ipre), cd = tanhfast(cpre), og = sigf(opre);
      float cn = fg * cst[r] + ig * cd;
      cst[r] = cn;
      hv[r] = og * tanhfast(cn);
    }

    // ---- transpose through LDS, then coalesced sc1 stores of out rows
    if (lo) {
      #pragma unroll
      for (int r = 0; r < 4; ++r) lds_o[wv][q * 4 + r][cc] = hv[r];
    }
    __syncthreads();
    {
      const int row = tid >> 2, i = tid & 3;    // 64 rows x 4 ull chunks
      ull v = ((const ull*)lds_o)[row * 4 + i];
      float* op = out + ((size_t)t << 16) + row * DLAT + wg * 8;
      AT_ST((ull*)op + i, v);
    }
    asm volatile("s_waitcnt vmcnt(0)" ::: "memory");   // h stores at MALL
    __syncthreads();                                   // all waves drained
    if (tid == 0) AT_ST(flags + wg, (unsigned)(t + 1));

    // ---- xg prefetch for t+1 (off critical path)
    {
      int tn = (t + 1 < T_STEPS) ? t + 1 : t;
      const unsigned short* xn = xbase + ((size_t)tn << 18);
      xp0 = *(const short4v*)(xn);
      xp1 = *(const short4v*)(xn + 256);
    }
    __syncthreads();   // protect lds_o from next step's writes
  }
}

extern "C" void kernel_launch(void* const* d_in, const int* in_sizes, int n_in,
                              void* d_out, int out_size, void* d_ws, size_t ws_size,
                              hipStream_t stream) {
  (void)in_sizes; (void)n_in; (void)out_size; (void)ws_size;
  const float* x   = (const float*)d_in[0];
  const float* Wf  = (const float*)d_in[1];
  const float* bfp = (const float*)d_in[2];
  const float* Wi  = (const float*)d_in[3];
  const float* bip = (const float*)d_in[4];
  const float* Wc  = (const float*)d_in[5];
  const float* bcp = (const float*)d_in[6];
  const float* Wo  = (const float*)d_in[7];
  const float* bop = (const float*)d_in[8];
  float* out = (float*)d_out;

  unsigned int*   flags = (unsigned int*)d_ws;
  unsigned short* xg    = (unsigned short*)((char*)d_ws + WS_XG);

  hipMemsetAsync(d_ws, 0, 4096, stream);   // reset arrival flags each call
  lstm_phase1<<<dim3(32, 128), 256, 0, stream>>>(x, Wf, bfp, Wi, bip, Wc, bcp, Wo, bop, xg);
  lstm_phase2<<<dim3(NWG), 256, 0, stream>>>(Wf, Wi, Wc, Wo, xg, flags, out);
}

// Round 6
// 7763.494 us; speedup vs baseline: 1.1602x; 1.0847x over previous
//
#include <hip/hip_runtime.h>
#include <hip/hip_bf16.h>

// LSTM: T=512, B=64, D_IN=512, D_LAT=1024.
// Phase 1: xg = x @ Wx^T + b (bf16 MFMA, pre-permuted bf16 output). Unchanged.
// Phase 2: persistent, 128 compute WGs x 256 thr (wave = 16 batch rows x 32
//   gate cols, 64 MFMA/step) + 1 AGGREGATOR WG. Wh in VGPRs.
//   Sync (the round-5 lesson: poll contention at the coherence point was the
//   bottleneck, not h movement):
//     producer wave: h sc1-store -> vmcnt(0) -> per-WAVE flag (512 flags)
//     aggregator WG: polls 512 flags, publishes epoch to 8 replicated lines
//     consumer wave: lane0 polls ONE epoch line (1 sc1 load/iter), then PLAIN
//       cached f32 loads of out[t-1] (L2 multicast), cvt_pk_bf16, MFMA.
//   Zero __syncthreads in the recurrence loop (wave-local LDS transpose).

typedef __attribute__((ext_vector_type(8))) short short8;
typedef __attribute__((ext_vector_type(4))) short short4v;
typedef __attribute__((ext_vector_type(4))) float f32x4;
typedef unsigned long long ull;

#define T_STEPS 512
#define BATCH   64
#define DIN     512
#define DLAT    1024
#define NWG     128

#define WS_XG   4096    // flags[512] @0, epoch lines @2048..3071, xg @4096

#define MFMA(a, b, c) __builtin_amdgcn_mfma_f32_16x16x32_bf16((a), (b), (c), 0, 0, 0)
#define AT_LD(p)    __hip_atomic_load((p), __ATOMIC_RELAXED, __HIP_MEMORY_SCOPE_AGENT)
#define AT_ST(p, v) __hip_atomic_store((p), (v), __ATOMIC_RELAXED, __HIP_MEMORY_SCOPE_AGENT)

static __device__ __forceinline__ unsigned short f2bf(float f) {
  unsigned u = __builtin_bit_cast(unsigned, f);
  u = (u + 0x7FFFu + ((u >> 16) & 1u)) >> 16;   // RNE
  return (unsigned short)u;
}
static __device__ __forceinline__ float bf2f(unsigned short s) {
  unsigned u = ((unsigned)s) << 16;
  return __builtin_bit_cast(float, u);
}
static __device__ __forceinline__ float sigf(float x) {
  return 1.0f / (1.0f + __expf(-x));
}
static __device__ __forceinline__ float tanhfast(float x) {
  return 2.0f / (1.0f + __expf(-2.0f * x)) - 1.0f;
}
static __device__ __forceinline__ short8 packbf(f32x4 a, f32x4 b) {
  short8 s;
  s[0]=(short)f2bf(a[0]); s[1]=(short)f2bf(a[1]); s[2]=(short)f2bf(a[2]); s[3]=(short)f2bf(a[3]);
  s[4]=(short)f2bf(b[0]); s[5]=(short)f2bf(b[1]); s[6]=(short)f2bf(b[2]); s[7]=(short)f2bf(b[3]);
  return s;
}
// HW RNE f32->bf16 pack (2 per instr); elem order matches packbf
static __device__ __forceinline__ short8 cvt8(f32x4 a, f32x4 b) {
  union { unsigned u[4]; short8 s; } r;
  asm("v_cvt_pk_bf16_f32 %0, %1, %2" : "=v"(r.u[0]) : "v"(a[0]), "v"(a[1]));
  asm("v_cvt_pk_bf16_f32 %0, %1, %2" : "=v"(r.u[1]) : "v"(a[2]), "v"(a[3]));
  asm("v_cvt_pk_bf16_f32 %0, %1, %2" : "=v"(r.u[2]) : "v"(b[0]), "v"(b[1]));
  asm("v_cvt_pk_bf16_f32 %0, %1, %2" : "=v"(r.u[3]) : "v"(b[2]), "v"(b[3]));
  return r.s;
}

// ---------------- Phase 1: xg = x @ Wx^T + bias (unchanged) -----------------
__global__ __launch_bounds__(256, 2) void lstm_phase1(
    const float* __restrict__ x,
    const float* __restrict__ Wf, const float* __restrict__ bfp,
    const float* __restrict__ Wi, const float* __restrict__ bip,
    const float* __restrict__ Wc, const float* __restrict__ bcp,
    const float* __restrict__ Wo, const float* __restrict__ bop,
    unsigned short* __restrict__ xg)
{
  __shared__ __align__(16) short lds[BATCH * DIN];
  const int tid  = threadIdx.x;
  const int nb   = blockIdx.x;    // 0..31
  const int tb4  = blockIdx.y;    // 0..127
  const int lane = tid & 63;
  const int wv   = tid >> 6;
  const int cc   = lane & 15;
  const int q    = lane >> 4;

  const int wg = nb * 4 + wv;     // N-slice 0..127
  const int jj = wg * 8 + (cc & 7);
  short8 bw[2][16];
  #pragma unroll
  for (int T = 0; T < 2; ++T) {
    const float* Wp = (T == 0) ? (cc < 8 ? Wf : Wi) : (cc < 8 ? Wc : Wo);
    const float* base = Wp + (size_t)jj * (DIN + DLAT);
    #pragma unroll
    for (int k = 0; k < 16; ++k) {
      const f32x4* p = (const f32x4*)(base + k * 32 + q * 8);
      bw[T][k] = packbf(p[0], p[1]);
    }
  }
  float biasv[2];
  biasv[0] = (cc < 8 ? bfp : bip)[jj];
  biasv[1] = (cc < 8 ? bcp : bop)[jj];

  for (int tt = 0; tt < 4; ++tt) {
    const int tb = tb4 * 4 + tt;
    const float* xs = x + (size_t)tb * (BATCH * DIN);
    #pragma unroll
    for (int it = 0; it < 16; ++it) {
      int c = tid + 256 * it;
      int row = c >> 6, kc = c & 63;
      const f32x4* p = (const f32x4*)(xs + row * DIN + kc * 8);
      f32x4 v0 = p[0], v1 = p[1];
      int byte = (row * (DIN * 2) + kc * 16) ^ ((row & 7) << 4);
      *(short8*)((char*)lds + byte) = packbf(v0, v1);
    }
    __syncthreads();

    f32x4 acc[4][2] = {};
    #pragma unroll
    for (int k = 0; k < 16; ++k) {
      #pragma unroll
      for (int m = 0; m < 4; ++m) {
        int row = m * 16 + cc;
        int byte = (row * (DIN * 2) + (k * 32 + q * 8) * 2) ^ ((row & 7) << 4);
        short8 a = *(const short8*)((const char*)lds + byte);
        acc[m][0] = MFMA(a, bw[0][k], acc[m][0]);
        acc[m][1] = MFMA(a, bw[1][k], acc[m][1]);
      }
    }
    __syncthreads();

    #pragma unroll
    for (int T = 0; T < 2; ++T) {
      float bias = biasv[T];
      #pragma unroll
      for (int m = 0; m < 4; ++m) {
        f32x4 g = acc[m][T];
        short4v s;
        s[0] = (short)f2bf(g[0] + bias);
        s[1] = (short)f2bf(g[1] + bias);
        s[2] = (short)f2bf(g[2] + bias);
        s[3] = (short)f2bf(g[3] + bias);
        size_t idx = ((((size_t)tb * NWG + wg) * 4 + m) * 2 + T) * 64 + lane;
        *(short4v*)(xg + idx * 4) = s;
      }
    }
  }
}

// ---------------- Phase 2: persistent recurrence ----------------------------
__global__ __launch_bounds__(256, 1) void lstm_phase2(
    const float* __restrict__ Wf, const float* __restrict__ Wi,
    const float* __restrict__ Wc, const float* __restrict__ Wo,
    const unsigned short* __restrict__ xg,
    unsigned int* __restrict__ flags,   // [512] per-wave flags; epoch @ +512
    float* __restrict__ out)            // out[t] IS h_t (f32)
{
  const int tid  = threadIdx.x;
  const int lane = tid & 63;
  const int wv   = tid >> 6;
  const int wg   = blockIdx.x;          // 0..127 compute, 128 aggregator
  unsigned int* epoch = flags + 512;    // 8 lines, 32 words (128 B) apart

  // ===================== aggregator WG =====================
  if (wg == NWG) {
    const unsigned int* fp = flags + lane;
    for (int t = 1; t < T_STEPS; ++t) {
      for (;;) {
        unsigned ok = 1;
        #pragma unroll
        for (int i = 0; i < 8; ++i)
          ok &= (AT_LD(fp + i * 64) >= (unsigned)t) ? 1u : 0u;
        if (__all(ok)) break;
        __builtin_amdgcn_s_sleep(1);
      }
      if (lane < 2) AT_ST(epoch + (wv * 2 + lane) * 32, (unsigned)t);
    }
    return;
  }

  // ===================== compute WGs =====================
  __shared__ __align__(16) float lds_t[4][16][8];   // per-wave transpose block

  const int cc   = lane & 15;
  const int q    = lane >> 4;
  const int jj   = wg * 8 + (cc & 7);
  const int widx = wg * 4 + wv;                 // per-wave flag index

  // Wh fragments -> registers
  short8 wh[2][32];
  #pragma unroll
  for (int T = 0; T < 2; ++T) {
    const float* Wp = (T == 0) ? (cc < 8 ? Wf : Wi) : (cc < 8 ? Wc : Wo);
    const float* base = Wp + (size_t)jj * (DIN + DLAT) + DIN;
    #pragma unroll
    for (int k = 0; k < 32; ++k) {
      const f32x4* p = (const f32x4*)(base + k * 32 + q * 8);
      wh[T][k] = packbf(p[0], p[1]);
    }
  }

  f32x4 cst = {0.f, 0.f, 0.f, 0.f};
  const unsigned short* xbase = xg + (((size_t)widx) * 2) * 256 + (size_t)lane * 4;
  const int arow = wv * 16 + cc;
  const unsigned int* ep = epoch + (widx & 7) * 32;

  short4v xp0 = *(const short4v*)(xbase);
  short4v xp1 = *(const short4v*)(xbase + 256);

  for (int t = 0; t < T_STEPS; ++t) {
    f32x4 acc0 = {0.f,0.f,0.f,0.f}, acc1 = {0.f,0.f,0.f,0.f};

    if (t > 0) {
      // ---- wait: lane0 polls one epoch replica line
      for (;;) {
        unsigned e = (lane == 0) ? AT_LD(ep) : 0u;
        e = (unsigned)__shfl((int)e, 0, 64);
        if (e >= (unsigned)t) break;
        __builtin_amdgcn_s_sleep(1);
      }
      // ---- h_{t-1} = out[t-1], PLAIN cached f32 loads (L2-multicast)
      const float* hrow = out + (((size_t)(t - 1)) << 16) + arow * DLAT + q * 8;
      #pragma unroll
      for (int chunk = 0; chunk < 2; ++chunk) {
        f32x4 r0[16], r1[16];
        #pragma unroll
        for (int k = 0; k < 16; ++k) {
          const f32x4* p = (const f32x4*)(hrow + (chunk * 16 + k) * 32);
          r0[k] = p[0];
          r1[k] = p[1];
        }
        #pragma unroll
        for (int k = 0; k < 16; ++k) {
          short8 a = cvt8(r0[k], r1[k]);
          acc0 = MFMA(a, wh[0][chunk * 16 + k], acc0);
          acc1 = MFMA(a, wh[1][chunk * 16 + k], acc1);
        }
      }
    }

    // ---- gates
    f32x4 g0, g1;
    #pragma unroll
    for (int r = 0; r < 4; ++r) {
      g0[r] = acc0[r] + bf2f((unsigned short)xp0[r]);
      g1[r] = acc1[r] + bf2f((unsigned short)xp1[r]);
    }
    f32x4 g0x, g1x;
    #pragma unroll
    for (int r = 0; r < 4; ++r) {
      g0x[r] = __shfl_xor(g0[r], 8, 64);
      g1x[r] = __shfl_xor(g1[r], 8, 64);
    }
    const bool lo = (cc < 8);
    float hv[4];
    #pragma unroll
    for (int r = 0; r < 4; ++r) {
      float fpre = lo ? g0[r]  : g0x[r];
      float ipre = lo ? g0x[r] : g0[r];
      float cpre = lo ? g1[r]  : g1x[r];
      float opre = lo ? g1x[r] : g1[r];
      float fg = sigf(fpre), ig = sigf(ipre), cd = tanhfast(cpre), og = sigf(opre);
      float cn = fg * cst[r] + ig * cd;
      cst[r] = cn;
      hv[r] = og * tanhfast(cn);
    }

    // ---- wave-local transpose (16 rows x 8 cols), no cross-wave barrier
    if (lo) {
      #pragma unroll
      for (int r = 0; r < 4; ++r) lds_t[wv][q * 4 + r][cc] = hv[r];
    }
    asm volatile("s_waitcnt lgkmcnt(0)" ::: "memory");
    {
      const int row16 = lane >> 2, ch = lane & 3;
      ull v = *(const ull*)&lds_t[wv][row16][ch * 2];
      float* op = out + ((size_t)t << 16) + (size_t)(wv * 16 + row16) * DLAT + wg * 8 + ch * 2;
      AT_ST((ull*)op, v);
    }
    asm volatile("s_waitcnt vmcnt(0)" ::: "memory");   // h at coherence point
    if (lane == 0) AT_ST(flags + widx, (unsigned)(t + 1));

    // ---- xg prefetch for t+1 (off critical path)
    {
      int tn = (t + 1 < T_STEPS) ? t + 1 : t;
      const unsigned short* xn = xbase + ((size_t)tn << 18);
      xp0 = *(const short4v*)(xn);
      xp1 = *(const short4v*)(xn + 256);
    }
  }
}

extern "C" void kernel_launch(void* const* d_in, const int* in_sizes, int n_in,
                              void* d_out, int out_size, void* d_ws, size_t ws_size,
                              hipStream_t stream) {
  (void)in_sizes; (void)n_in; (void)out_size; (void)ws_size;
  const float* x   = (const float*)d_in[0];
  const float* Wf  = (const float*)d_in[1];
  const float* bfp = (const float*)d_in[2];
  const float* Wi  = (const float*)d_in[3];
  const float* bip = (const float*)d_in[4];
  const float* Wc  = (const float*)d_in[5];
  const float* bcp = (const float*)d_in[6];
  const float* Wo  = (const float*)d_in[7];
  const float* bop = (const float*)d_in[8];
  float* out = (float*)d_out;

  unsigned int*   flags = (unsigned int*)d_ws;
  unsigned short* xg    = (unsigned short*)((char*)d_ws + WS_XG);

  hipMemsetAsync(d_ws, 0, 4096, stream);   // reset flags + epoch each call
  lstm_phase1<<<dim3(32, 128), 256, 0, stream>>>(x, Wf, bfp, Wi, bip, Wc, bcp, Wo, bop, xg);
  lstm_phase2<<<dim3(NWG + 1), 256, 0, stream>>>(Wf, Wi, Wc, Wo, xg, flags, out);
}